// Round 16
// baseline (173.207 us; speedup 1.0000x reference)
//
#include <hip/hip_runtime.h>

typedef _Float16 f16;
typedef _Float16 half8 __attribute__((ext_vector_type(8)));
typedef float f32x4 __attribute__((ext_vector_type(4)));
typedef unsigned int u32x4 __attribute__((ext_vector_type(4)));

#define RES 1024
#define NH 16
#define HD 64
#define BATCH 2
#define SEQ 2048
#define M_ROWS (BATCH * SEQ)

__device__ __forceinline__ void gload_lds16(const void* g, void* l) {
  __builtin_amdgcn_global_load_lds(
      (const __attribute__((address_space(1))) unsigned int*)g,
      (__attribute__((address_space(3))) unsigned int*)l, 16, 0, 0);
}

// pack two f32 -> one u32 of two f16 (round-toward-zero, single VALU op)
__device__ __forceinline__ unsigned pk16(float a, float b) {
  auto h = __builtin_amdgcn_cvt_pkrtz(a, b);  // __fp16 ext_vector(2)
  return __builtin_bit_cast(unsigned, h);
}

// RNE variant: packs (f16)a low, (f16)b high — bit-identical to scalar
// (f16) casts, so using it in the proj V-epilogue changes NO output bits.
__device__ __forceinline__ unsigned pk16_rne(float a, float b) {
  unsigned short la = __builtin_bit_cast(unsigned short, (f16)a);
  unsigned short hb = __builtin_bit_cast(unsigned short, (f16)b);
  return (unsigned)la | ((unsigned)hb << 16);
}

// x' = [a_lo32, b_lo32], y' = [a_hi32, b_hi32]
__device__ __forceinline__ void swap32(unsigned a, unsigned b, unsigned& x, unsigned& y) {
#if __has_builtin(__builtin_amdgcn_permlane32_swap)
  auto t = __builtin_amdgcn_permlane32_swap(a, b, false, false);
  x = (unsigned)t[0];
  y = (unsigned)t[1];
#else
  unsigned ax = __shfl_xor(a, 32), bx = __shfl_xor(b, 32);
  int hi = (threadIdx.x & 63) >> 5;
  x = hi ? bx : a;
  y = hi ? b : ax;
#endif
}

// rows of 16 lanes: x' = [a0,b0,a2,b2], y' = [a1,b1,a3,b3]
__device__ __forceinline__ void swap16(unsigned a, unsigned b, unsigned& x, unsigned& y) {
#if __has_builtin(__builtin_amdgcn_permlane16_swap)
  auto t = __builtin_amdgcn_permlane16_swap(a, b, false, false);
  x = (unsigned)t[0];
  y = (unsigned)t[1];
#else
  unsigned ax = __shfl_xor(a, 16), bx = __shfl_xor(b, 16);
  int q1 = ((threadIdx.x & 63) >> 4) & 1;
  x = q1 ? bx : a;
  y = q1 ? b : ax;
#endif
}

// ---------------- prep: x fp32->fp16 + W transpose, merged (v22, kept) ----------------
__global__ __launch_bounds__(256) void prep_kernel(const float* __restrict__ x,
                                                   const float* __restrict__ Wq,
                                                   const float* __restrict__ Wk,
                                                   const float* __restrict__ Wv,
                                                   f16* __restrict__ xh,
                                                   f16* __restrict__ Wt) {
  __shared__ float tile[32][33];
  int bid = blockIdx.x;
  int tid = threadIdx.x;
  if (bid < 2048) {
    // ---- x: fp32 -> fp16, 8 floats per thread ----
    int idx = bid * 256 + tid;
    const float4* xv = (const float4*)x;
    float4 a = xv[idx * 2];
    float4 b = xv[idx * 2 + 1];
    half8 h;
    h[0] = (f16)a.x; h[1] = (f16)a.y; h[2] = (f16)a.z; h[3] = (f16)a.w;
    h[4] = (f16)b.x; h[5] = (f16)b.y; h[6] = (f16)b.z; h[7] = (f16)b.w;
    ((half8*)xh)[idx] = h;
  } else {
    // ---- W: fp32 [K,N] -> fp16 W^T [N,K], 32x32 tile per block ----
    int wb = bid - 2048;        // 0..3071
    int bz = wb >> 10;          // proj 0..2
    int rem = wb & 1023;
    int by = rem >> 5, bx = rem & 31;
    const float* W = bz == 0 ? Wq : (bz == 1 ? Wk : Wv);
    f16* Wo = Wt + (size_t)bz * RES * RES;
    int tx = tid & 31, ty = tid >> 5;  // ty 0..7
#pragma unroll
    for (int i = 0; i < 4; i++)
      tile[ty + i * 8][tx] = W[(size_t)(by * 32 + ty + i * 8) * RES + bx * 32 + tx];
    __syncthreads();
#pragma unroll
    for (int i = 0; i < 4; i++)
      Wo[(size_t)(bx * 32 + ty + i * 8) * RES + by * 32 + tx] = (f16)tile[tx][ty + i * 8];
  }
}

// ---------------- projections: C = x @ W  (B^T layout) — v23: 256^2 8-wave ----------------
// r10 measured proj at ~55-58us, MfmaUtil 17.7% — the 2-phase 128^2
// structural ceiling. v23 moves to the 256^2 regime (guide: tile 256^2 +
// counted-vmcnt dbuf + LDS read-swizzle = 1.7x on identical math):
//  - 512 threads / 8 waves (2M x 4N); per-wave output 128x64 (acc[8][4]).
//  - BK=64; LDS 2 x (256x64 A + 256x64 B) f16 = 128KB, double-buffered.
//  - Staging = flash's proven pre-swizzled-global + linear-LDS-dest pattern
//    (pc = chunk ^ (row&7)); reads use the matching XOR -> conflict-free
//    ds_read_b128 at 128B row stride (unswizzled would be 16-way).
//  - Schedule = r18's numerics-proven counted-vmcnt shape: stage(t+1) ->
//    vmcnt(8) [8 gloads/stage, in-order retirement => tile t landed] ->
//    s_barrier -> frags+MFMA (per-half to bound VGPR) -> s_barrier.
//    This matters HERE because grid 192 < 256 CUs => no cross-block TLP
//    to hide drains (why r11's pipeline was null at 3 blocks/CU).
//  - K accumulation order unchanged (k 0..31 then 32..63 per 64-step) =>
//    Qh/Kh/Vt BIT-IDENTICAL to v22 => flash inputs identical.
// Epilogues: Q/K scalar (32B segments, as r9); Vt vectorized via the
// session-proven swap32/swap16 repack (v22), applied per 64-row group.
__global__ __launch_bounds__(512) void proj_gemm_kernel(const f16* __restrict__ xh,
                                                        const f16* __restrict__ Wt,
                                                        f16* __restrict__ Qh,
                                                        f16* __restrict__ Kh,
                                                        f16* __restrict__ Vt) {
  int proj = blockIdx.z;
  const f16* Bt = Wt + (size_t)proj * RES * RES;
  int m0 = blockIdx.x * 256;
  int n0 = blockIdx.y * 256;
  __shared__ alignas(16) f16 Als[2][256 * 64];
  __shared__ alignas(16) f16 Bls[2][256 * 64];
  int tid = threadIdx.x, lane = tid & 63, w = tid >> 6;  // w 0..7
  int l15 = lane & 15, quad = lane >> 4;
  int wr = w >> 2, wc = w & 3;  // 2 x 4 wave grid

  f32x4 zero = {0.f, 0.f, 0.f, 0.f};
  f32x4 acc[8][4];
#pragma unroll
  for (int mt = 0; mt < 8; mt++)
#pragma unroll
    for (int nt = 0; nt < 4; nt++) acc[mt][nt] = zero;

  // stage one 256x64 A-tile + B-tile into buffer pb (8 gloads per thread).
  // round rnd covers rows rnd*64 + (tid>>3); chunk tid&7 (8 f16 = 16B).
  // Global source chunk pre-swizzled: pc = chunk ^ (row&7); LDS dest linear
  // (wave-uniform base + lane*16B: base covers rows rnd*64 + w*8).
  auto stageAB = [&](int k0, int pb) {
#pragma unroll
    for (int rnd = 0; rnd < 4; rnd++) {
      int row = rnd * 64 + (tid >> 3);
      int pc = (tid & 7) ^ (row & 7);
      gload_lds16(xh + (size_t)(m0 + row) * RES + k0 + pc * 8,
                  &Als[pb][rnd * 4096 + w * 512]);
      gload_lds16(Bt + (size_t)(n0 + row) * RES + k0 + pc * 8,
                  &Bls[pb][rnd * 4096 + w * 512]);
    }
  };

  constexpr int KSTEPS = RES / 64;  // 16
  stageAB(0, 0);

  for (int it = 0; it < KSTEPS; ++it) {
    int pb = it & 1;
    if (it + 1 < KSTEPS) {
      stageAB((it + 1) * 64, pb ^ 1);  // prefetch next tile into other buffer
      asm volatile("s_waitcnt vmcnt(8)" ::: "memory");  // tile `it` landed
    } else {
      asm volatile("s_waitcnt vmcnt(0)" ::: "memory");
    }
    __builtin_amdgcn_sched_barrier(0);
    __builtin_amdgcn_s_barrier();  // all waves: tile `it` resident
    __builtin_amdgcn_sched_barrier(0);

#pragma unroll
    for (int half = 0; half < 2; half++) {  // k sub-step of 32
      half8 af[8], bf[4];
#pragma unroll
      for (int mt = 0; mt < 8; mt++) {
        int arow = wr * 128 + mt * 16 + l15;
        af[mt] = *(const half8*)&Als[pb][arow * 64 + ((half * 4 + quad) ^ (arow & 7)) * 8];
      }
#pragma unroll
      for (int nt = 0; nt < 4; nt++) {
        int brow = wc * 64 + nt * 16 + l15;
        bf[nt] = *(const half8*)&Bls[pb][brow * 64 + ((half * 4 + quad) ^ (brow & 7)) * 8];
      }
#pragma unroll
      for (int mt = 0; mt < 8; mt++)
#pragma unroll
        for (int nt = 0; nt < 4; nt++)
          acc[mt][nt] = __builtin_amdgcn_mfma_f32_16x16x32_f16(af[mt], bf[nt], acc[mt][nt], 0, 0, 0);
    }

    __builtin_amdgcn_sched_barrier(0);
    __builtin_amdgcn_s_barrier();  // frag reads of buf pb complete block-wide
    __builtin_amdgcn_sched_barrier(0);
  }

  // ---- epilogue ----
  int rowbase = m0 + wr * 128;           // 128-aligned; cannot cross b boundary
  int b = rowbase >> 11;
  int sbase = rowbase & (SEQ - 1);
  int colbase = n0 + wc * 64;            // 64-aligned -> single head per wave
  int h = colbase >> 6;
  size_t bh = (size_t)b * NH + h;

  if (proj == 2) {
    // vectorized Vt: lane gets 8 consecutive s for fixed d (v22-proven)
#pragma unroll
    for (int nt = 0; nt < 4; nt++) {
      int d = nt * 16 + l15;
#pragma unroll
      for (int g = 0; g < 2; g++) {  // 64-row groups: mt 0..3 and 4..7
        unsigned wp[4][2];
#pragma unroll
        for (int mtl = 0; mtl < 4; mtl++) {
          wp[mtl][0] = pk16_rne(acc[g * 4 + mtl][nt][0], acc[g * 4 + mtl][nt][1]);
          wp[mtl][1] = pk16_rne(acc[g * 4 + mtl][nt][2], acc[g * 4 + mtl][nt][3]);
        }
#pragma unroll
        for (int ks = 0; ks < 2; ks++) {
          u32x4 pw;
#pragma unroll
          for (int i = 0; i < 2; i++) {
            unsigned a, bb2, xx, yy;
            swap32(wp[2 * ks][i], wp[2 * ks + 1][i], a, bb2);
            swap16(a, bb2, xx, yy);
            pw[i] = xx;
            pw[2 + i] = yy;
          }
          int s0 = sbase + g * 64 + ks * 32 + quad * 8;
          *(half8*)&Vt[(bh * HD + d) * SEQ + s0] = __builtin_bit_cast(half8, pw);
        }
      }
    }
  } else {
#pragma unroll
    for (int mt = 0; mt < 8; mt++) {
#pragma unroll
      for (int nt = 0; nt < 4; nt++) {
#pragma unroll
        for (int r = 0; r < 4; r++) {
          int s = sbase + mt * 16 + quad * 4 + r;
          int d = nt * 16 + l15;
          f16 v = (f16)acc[mt][nt][r];
          if (proj == 0)
            Qh[(bh * SEQ + s) * HD + d] = v;
          else
            Kh[(bh * SEQ + s) * HD + d] = v;
        }
      }
    }
  }
}

// ---------------- flash attention (v21 = round-9-verified v16, verbatim) ----------------
// UNTOUCHED. 8/8 passing runs with this exact source. Every structural
// variant (in-block KV split, cross-block KV split, QSCALE+setprio,
// q-split x2) failed numerics with a codegen-sensitive mechanism (v19 vs
// v20: identical math, different launch_bounds, different error).
__global__ __launch_bounds__(128, 3) void flash_kernel(const f16* __restrict__ Qh,
                                                       const f16* __restrict__ Kh,
                                                       const f16* __restrict__ Vt,
                                                       float* __restrict__ out) {
  int L = blockIdx.x;
  int xcd = L & 7, slot = L >> 3;
  int bh = ((slot >> 5) << 3) | xcd;  // 32 qt-blocks of bh share one XCD
  int qt = slot & 31;
  int b = bh >> 4, h = bh & 15;
  int tid = threadIdx.x;
  int lane = tid & 63, w = tid >> 6;  // w in {0,1}
  int l15 = lane & 15, quad = lane >> 4;
  int qrow0 = qt * 64 + w * 32;

  __shared__ alignas(16) f16 Kls[64 * 64];  // [t][d], XOR chunk swizzle by row&7
  __shared__ alignas(16) f16 Vls[64 * 64];  // [d][t], same swizzle

  const f16* kbase = Kh + (size_t)bh * SEQ * HD;
  const f16* vbase = Vt + (size_t)bh * HD * SEQ;

  // staging map: 128 threads, 4 rounds x (K,V); round rd covers rows rd*16 + (tid>>3)
  int srow = tid >> 3;  // 0..15
  int schunk = tid & 7;

  // Q fragments (B-operand for S^T = K Q^T), 2 q-tiles; fold in 1/sqrt(64)
  const f16* qptr = Qh + ((size_t)bh * SEQ + qrow0 + l15) * HD + quad * 8;
  half8 qf[2][2];
  qf[0][0] = *(const half8*)qptr;
  qf[0][1] = *(const half8*)(qptr + 32);
  qf[1][0] = *(const half8*)(qptr + 16 * HD);
  qf[1][1] = *(const half8*)(qptr + 16 * HD + 32);
#pragma unroll
  for (int q2 = 0; q2 < 2; q2++)
#pragma unroll
    for (int ks = 0; ks < 2; ks++)
#pragma unroll
      for (int j = 0; j < 8; j++) qf[q2][ks][j] *= (f16)0.125f;

  f32x4 zero = {0.f, 0.f, 0.f, 0.f};
  float l_acc[2] = {0.f, 0.f};
  f32x4 o[2][4];
#pragma unroll
  for (int q2 = 0; q2 < 2; q2++)
#pragma unroll
    for (int nt = 0; nt < 4; nt++) o[q2][nt] = zero;

  // swizzled LDS read offsets (halves): row*64 + (chunk ^ (row&7))*8
  int swz0 = (quad ^ (l15 & 7)) * 8;        // log chunks 0..3
  int swz1 = ((quad + 4) ^ (l15 & 7)) * 8;  // log chunks 4..7

  // cooperative staging: K tile (64t x 64d) + V tile (64d x 64t)
  auto stage = [&](int kv0) {
#pragma unroll
    for (int rd = 0; rd < 4; rd++) {
      int row = rd * 16 + srow;
      int pc = schunk ^ (row & 7);
      gload_lds16(kbase + ((size_t)(kv0 + row) << 6) + pc * 8,
                  &Kls[rd * 1024 + w * 512]);
      gload_lds16(vbase + ((size_t)row * SEQ) + kv0 + pc * 8,
                  &Vls[rd * 1024 + w * 512]);
    }
  };

  stage(0);

  for (int kv0 = 0; kv0 < SEQ; kv0 += 64) {
    __syncthreads();  // staged tile visible (barrier drains vmcnt)

    // ---- K fragments from LDS (shared across both q-tiles) ----
    half8 kf0[4], kf1[4];
#pragma unroll
    for (int tt = 0; tt < 4; tt++) {
      int row = tt * 16 + l15;
      kf0[tt] = *(const half8*)&Kls[row * 64 + swz0];
      kf1[tt] = *(const half8*)&Kls[row * 64 + swz1];
    }

    // ---- per q-tile: S^T, softmax, in-register P repack ----
    half8 pa[2][2];  // PV A-fragments, k-slice ks
#pragma unroll
    for (int q2 = 0; q2 < 2; q2++) {
      f32x4 sc[4];
#pragma unroll
      for (int tt = 0; tt < 4; tt++) {
        sc[tt] = __builtin_amdgcn_mfma_f32_16x16x32_f16(kf0[tt], qf[q2][0], zero, 0, 0, 0);
        sc[tt] = __builtin_amdgcn_mfma_f32_16x16x32_f16(kf1[tt], qf[q2][1], sc[tt], 0, 0, 0);
      }
      float ps = 0.f;
#pragma unroll
      for (int tt = 0; tt < 4; tt++)
#pragma unroll
        for (int r = 0; r < 4; r++) { sc[tt][r] = __expf(sc[tt][r]); ps += sc[tt][r]; }
      ps += __shfl_xor(ps, 16);
      ps += __shfl_xor(ps, 32);
      l_acc[q2] += ps;

      // pack P to f16 words: W[tt][0]=(p0,p1), W[tt][1]=(p2,p3)
      unsigned wp[4][2];
#pragma unroll
      for (int tt = 0; tt < 4; tt++) {
        wp[tt][0] = pk16(sc[tt][0], sc[tt][1]);
        wp[tt][1] = pk16(sc[tt][2], sc[tt][3]);
      }
      // route to A-fragment layout: pa[ks][j] = P[l15][ks*32+quad*8+j]
#pragma unroll
      for (int ks = 0; ks < 2; ks++) {
        u32x4 pw;
#pragma unroll
        for (int i = 0; i < 2; i++) {
          unsigned a, bb, x, y;
          swap32(wp[2 * ks][i], wp[2 * ks + 1][i], a, bb);
          swap16(a, bb, x, y);
          pw[i] = x;       // j = 4*i .. 4*i+1  (half 0)
          pw[2 + i] = y;   // j = 4+... (half 1)
        }
        pa[q2][ks] = __builtin_bit_cast(half8, pw);
      }
    }

    // ---- V fragments from LDS (shared across both q-tiles) ----
    half8 vf0[4], vf1[4];
#pragma unroll
    for (int nt = 0; nt < 4; nt++) {
      int row = nt * 16 + l15;
      vf0[nt] = *(const half8*)&Vls[row * 64 + swz0];
      vf1[nt] = *(const half8*)&Vls[row * 64 + swz1];
    }

    __syncthreads();  // all K/V LDS reads of this tile complete

    if (kv0 + 64 < SEQ) stage(kv0 + 64);  // issue next tile; hides under PV

    // ---- O += P V (pure register) ----
#pragma unroll
    for (int q2 = 0; q2 < 2; q2++)
#pragma unroll
      for (int ks = 0; ks < 2; ks++)
#pragma unroll
        for (int nt = 0; nt < 4; nt++)
          o[q2][nt] = __builtin_amdgcn_mfma_f32_16x16x32_f16(pa[q2][ks], ks ? vf1[nt] : vf0[nt], o[q2][nt], 0, 0, 0);
  }

#pragma unroll
  for (int q2 = 0; q2 < 2; q2++) {
    float linv[4];
#pragma unroll
    for (int r = 0; r < 4; r++) linv[r] = 1.0f / __shfl(l_acc[q2], quad * 4 + r);
#pragma unroll
    for (int nt = 0; nt < 4; nt++) {
#pragma unroll
      for (int r = 0; r < 4; r++) {
        int s = qrow0 + q2 * 16 + quad * 4 + r;
        out[((size_t)b * SEQ + s) * RES + h * HD + nt * 16 + l15] = o[q2][nt][r] * linv[r];
      }
    }
  }
}

extern "C" void kernel_launch(void* const* d_in, const int* in_sizes, int n_in,
                              void* d_out, int out_size, void* d_ws, size_t ws_size,
                              hipStream_t stream) {
  (void)in_sizes; (void)n_in; (void)out_size; (void)ws_size;
  const float* x  = (const float*)d_in[0];
  const float* Wq = (const float*)d_in[1];
  const float* Wk = (const float*)d_in[2];
  const float* Wv = (const float*)d_in[3];
  float* out = (float*)d_out;

  // workspace layout (fp16): xh 8MB | Wt 6MB | Qh 8MB | Kh 8MB | Vt 8MB = 38MB
  f16* xh = (f16*)d_ws;
  f16* Wt = xh + (size_t)M_ROWS * RES;
  f16* Qh = Wt + (size_t)3 * RES * RES;
  f16* Kh = Qh + (size_t)BATCH * NH * SEQ * HD;
  f16* Vt = Kh + (size_t)BATCH * NH * SEQ * HD;

  prep_kernel<<<2048 + 3072, 256, 0, stream>>>(x, Wq, Wk, Wv, xh, Wt);
  proj_gemm_kernel<<<dim3(M_ROWS / 256, RES / 256, 3), 512, 0, stream>>>(xh, Wt, Qh, Kh, Vt);
  flash_kernel<<<1024, 128, 0, stream>>>(Qh, Kh, Vt, out);
}

// Round 17
// 164.835 us; speedup vs baseline: 1.0508x; 1.0508x over previous
//
#include <hip/hip_runtime.h>

typedef _Float16 f16;
typedef _Float16 half8 __attribute__((ext_vector_type(8)));
typedef float f32x4 __attribute__((ext_vector_type(4)));
typedef unsigned int u32x4 __attribute__((ext_vector_type(4)));

#define RES 1024
#define NH 16
#define HD 64
#define BATCH 2
#define SEQ 2048
#define M_ROWS (BATCH * SEQ)

__device__ __forceinline__ void gload_lds16(const void* g, void* l) {
  __builtin_amdgcn_global_load_lds(
      (const __attribute__((address_space(1))) unsigned int*)g,
      (__attribute__((address_space(3))) unsigned int*)l, 16, 0, 0);
}

// pack two f32 -> one u32 of two f16 (round-toward-zero, single VALU op)
__device__ __forceinline__ unsigned pk16(float a, float b) {
  auto h = __builtin_amdgcn_cvt_pkrtz(a, b);  // __fp16 ext_vector(2)
  return __builtin_bit_cast(unsigned, h);
}

// RNE variant: packs (f16)a low, (f16)b high — bit-identical to scalar
// (f16) casts, so using it in the proj V-epilogue changes NO output bits.
__device__ __forceinline__ unsigned pk16_rne(float a, float b) {
  unsigned short la = __builtin_bit_cast(unsigned short, (f16)a);
  unsigned short hb = __builtin_bit_cast(unsigned short, (f16)b);
  return (unsigned)la | ((unsigned)hb << 16);
}

// x' = [a_lo32, b_lo32], y' = [a_hi32, b_hi32]
__device__ __forceinline__ void swap32(unsigned a, unsigned b, unsigned& x, unsigned& y) {
#if __has_builtin(__builtin_amdgcn_permlane32_swap)
  auto t = __builtin_amdgcn_permlane32_swap(a, b, false, false);
  x = (unsigned)t[0];
  y = (unsigned)t[1];
#else
  unsigned ax = __shfl_xor(a, 32), bx = __shfl_xor(b, 32);
  int hi = (threadIdx.x & 63) >> 5;
  x = hi ? bx : a;
  y = hi ? b : ax;
#endif
}

// rows of 16 lanes: x' = [a0,b0,a2,b2], y' = [a1,b1,a3,b3]
__device__ __forceinline__ void swap16(unsigned a, unsigned b, unsigned& x, unsigned& y) {
#if __has_builtin(__builtin_amdgcn_permlane16_swap)
  auto t = __builtin_amdgcn_permlane16_swap(a, b, false, false);
  x = (unsigned)t[0];
  y = (unsigned)t[1];
#else
  unsigned ax = __shfl_xor(a, 16), bx = __shfl_xor(b, 16);
  int q1 = ((threadIdx.x & 63) >> 4) & 1;
  x = q1 ? bx : a;
  y = q1 ? b : ax;
#endif
}

// ---------------- prep: x fp32->fp16 + W transpose, merged (v22, kept) ----------------
__global__ __launch_bounds__(256) void prep_kernel(const float* __restrict__ x,
                                                   const float* __restrict__ Wq,
                                                   const float* __restrict__ Wk,
                                                   const float* __restrict__ Wv,
                                                   f16* __restrict__ xh,
                                                   f16* __restrict__ Wt) {
  __shared__ float tile[32][33];
  int bid = blockIdx.x;
  int tid = threadIdx.x;
  if (bid < 2048) {
    // ---- x: fp32 -> fp16, 8 floats per thread ----
    int idx = bid * 256 + tid;
    const float4* xv = (const float4*)x;
    float4 a = xv[idx * 2];
    float4 b = xv[idx * 2 + 1];
    half8 h;
    h[0] = (f16)a.x; h[1] = (f16)a.y; h[2] = (f16)a.z; h[3] = (f16)a.w;
    h[4] = (f16)b.x; h[5] = (f16)b.y; h[6] = (f16)b.z; h[7] = (f16)b.w;
    ((half8*)xh)[idx] = h;
  } else {
    // ---- W: fp32 [K,N] -> fp16 W^T [N,K], 32x32 tile per block ----
    int wb = bid - 2048;        // 0..3071
    int bz = wb >> 10;          // proj 0..2
    int rem = wb & 1023;
    int by = rem >> 5, bx = rem & 31;
    const float* W = bz == 0 ? Wq : (bz == 1 ? Wk : Wv);
    f16* Wo = Wt + (size_t)bz * RES * RES;
    int tx = tid & 31, ty = tid >> 5;  // ty 0..7
#pragma unroll
    for (int i = 0; i < 4; i++)
      tile[ty + i * 8][tx] = W[(size_t)(by * 32 + ty + i * 8) * RES + bx * 32 + tx];
    __syncthreads();
#pragma unroll
    for (int i = 0; i < 4; i++)
      Wo[(size_t)(bx * 32 + ty + i * 8) * RES + by * 32 + tx] = (f16)tile[tx][ty + i * 8];
  }
}

// ---------------- projections: C = x @ W  (B^T layout), m97-style — v24 ----------------
// v23 post-mortem: 256^2 tile passed numerics but regressed (173 vs 167) —
// the guide's regime table says 256^2+2-phase is null, and the shape gives
// only 192 blocks for 256 CUs (75% fill). Reverted to the v22 128^2 shape.
// v24's single change: kill the 3.15M SQ_LDS_BANK_CONFLICT r10 measured.
// Cause: fragment reads at 64B row stride — bank = (row*16+quad*4)%32 has
// only 4 distinct starts over 16 rows x 4 quads (2x over the b128 floor).
// Fix (flash's proven chunk-XOR family, 4-chunk rows): stage global chunk
// pc = chunk ^ f(row), f(row) = (row&3)^((row>>2)&3); LDS dest stays linear
// (gload_lds requirement); reads fetch chunk quad ^ f(row). Enumeration:
// start-banks become all 8 of {(row&1)*16 + c*4} -> uniform, conflict-free.
// Stored bits and all math IDENTICAL (placement permutation, both sides
// matched). Q/K epilogue scalar; Vt epilogue vectorized (v22-proven).
__global__ __launch_bounds__(256) void proj_gemm_kernel(const f16* __restrict__ xh,
                                                        const f16* __restrict__ Wt,
                                                        f16* __restrict__ Qh,
                                                        f16* __restrict__ Kh,
                                                        f16* __restrict__ Vt) {
  int proj = blockIdx.z;
  const f16* Bt = Wt + (size_t)proj * RES * RES;
  int m0 = blockIdx.x * 128;
  int n0 = blockIdx.y * 128;
  __shared__ alignas(16) f16 Als[128 * 32];
  __shared__ alignas(16) f16 Bls[128 * 32];
  int t = threadIdx.x, lane = t & 63, w = t >> 6;
  int l15 = lane & 15, quad = lane >> 4;
  int wm = w >> 1, wn = w & 1;

  f32x4 zero = {0.f, 0.f, 0.f, 0.f};
  f32x4 acc[4][4];
#pragma unroll
  for (int mt = 0; mt < 4; mt++)
#pragma unroll
    for (int nt = 0; nt < 4; nt++) acc[mt][nt] = zero;

  for (int k0 = 0; k0 < RES; k0 += 32) {
#pragma unroll
    for (int i = 0; i < 2; i++) {
      int wl = i * 256 + w * 64;   // wave-uniform linear base
      int linear = wl + lane;      // per-lane
      int row = linear >> 2;
      int f = (row & 3) ^ ((row >> 2) & 3);
      int pc = (linear & 3) ^ f;   // pre-swizzled global chunk
      gload_lds16(xh + (size_t)(m0 + row) * RES + k0 + pc * 8, &Als[wl * 8]);
      gload_lds16(Bt + (size_t)(n0 + row) * RES + k0 + pc * 8, &Bls[wl * 8]);
    }
    __syncthreads();
    half8 af[4], bf[4];
#pragma unroll
    for (int mt = 0; mt < 4; mt++) {
      int arow = wm * 64 + mt * 16 + l15;
      int fa = (arow & 3) ^ ((arow >> 2) & 3);
      af[mt] = *(const half8*)&Als[arow * 32 + (quad ^ fa) * 8];
    }
#pragma unroll
    for (int nt = 0; nt < 4; nt++) {
      int brow = wn * 64 + nt * 16 + l15;
      int fb = (brow & 3) ^ ((brow >> 2) & 3);
      bf[nt] = *(const half8*)&Bls[brow * 32 + (quad ^ fb) * 8];
    }
#pragma unroll
    for (int mt = 0; mt < 4; mt++)
#pragma unroll
      for (int nt = 0; nt < 4; nt++)
        acc[mt][nt] = __builtin_amdgcn_mfma_f32_16x16x32_f16(af[mt], bf[nt], acc[mt][nt], 0, 0, 0);
    __syncthreads();
  }

  if (proj == 2) {
    // ---- vectorized Vt epilogue: lane gets 8 consecutive s for fixed d ----
    int rowb = m0 + wm * 64;             // 64-aligned; cannot cross b boundary
    int b = rowb >> 11;
    int sbase = rowb & (SEQ - 1);
    int h = (n0 + wn * 64) >> 6;         // wave-uniform head
    size_t bh = (size_t)b * NH + h;
#pragma unroll
    for (int nt = 0; nt < 4; nt++) {
      unsigned wp[4][2];
#pragma unroll
      for (int mt = 0; mt < 4; mt++) {
        wp[mt][0] = pk16_rne(acc[mt][nt][0], acc[mt][nt][1]);
        wp[mt][1] = pk16_rne(acc[mt][nt][2], acc[mt][nt][3]);
      }
#pragma unroll
      for (int ks = 0; ks < 2; ks++) {
        u32x4 pw;
#pragma unroll
        for (int i = 0; i < 2; i++) {
          unsigned a, bb, xx, yy;
          swap32(wp[2 * ks][i], wp[2 * ks + 1][i], a, bb);
          swap16(a, bb, xx, yy);
          pw[i] = xx;
          pw[2 + i] = yy;
        }
        int d = nt * 16 + l15;
        int s0 = sbase + ks * 32 + quad * 8;
        *(half8*)&Vt[(bh * HD + d) * SEQ + s0] = __builtin_bit_cast(half8, pw);
      }
    }
  } else {
#pragma unroll
    for (int mt = 0; mt < 4; mt++) {
#pragma unroll
      for (int nt = 0; nt < 4; nt++) {
#pragma unroll
        for (int r = 0; r < 4; r++) {
          int row = m0 + wm * 64 + mt * 16 + quad * 4 + r;  // 0..4095
          int col = n0 + wn * 64 + nt * 16 + l15;           // 0..1023
          f16 v = (f16)acc[mt][nt][r];
          int b = row >> 11, s = row & (SEQ - 1);
          int h = col >> 6, d = col & (HD - 1);
          size_t bh = (size_t)b * NH + h;
          if (proj == 0)
            Qh[(bh * SEQ + s) * HD + d] = v;
          else
            Kh[(bh * SEQ + s) * HD + d] = v;
        }
      }
    }
  }
}

// ---------------- flash attention (v21 = round-9-verified v16, verbatim) ----------------
// UNTOUCHED. 9/9 passing runs with this exact source. Every structural
// variant (in-block KV split, cross-block KV split, QSCALE+setprio,
// q-split x2) failed numerics with a codegen-sensitive mechanism (v19 vs
// v20: identical math, different launch_bounds, different error).
__global__ __launch_bounds__(128, 3) void flash_kernel(const f16* __restrict__ Qh,
                                                       const f16* __restrict__ Kh,
                                                       const f16* __restrict__ Vt,
                                                       float* __restrict__ out) {
  int L = blockIdx.x;
  int xcd = L & 7, slot = L >> 3;
  int bh = ((slot >> 5) << 3) | xcd;  // 32 qt-blocks of bh share one XCD
  int qt = slot & 31;
  int b = bh >> 4, h = bh & 15;
  int tid = threadIdx.x;
  int lane = tid & 63, w = tid >> 6;  // w in {0,1}
  int l15 = lane & 15, quad = lane >> 4;
  int qrow0 = qt * 64 + w * 32;

  __shared__ alignas(16) f16 Kls[64 * 64];  // [t][d], XOR chunk swizzle by row&7
  __shared__ alignas(16) f16 Vls[64 * 64];  // [d][t], same swizzle

  const f16* kbase = Kh + (size_t)bh * SEQ * HD;
  const f16* vbase = Vt + (size_t)bh * HD * SEQ;

  // staging map: 128 threads, 4 rounds x (K,V); round rd covers rows rd*16 + (tid>>3)
  int srow = tid >> 3;  // 0..15
  int schunk = tid & 7;

  // Q fragments (B-operand for S^T = K Q^T), 2 q-tiles; fold in 1/sqrt(64)
  const f16* qptr = Qh + ((size_t)bh * SEQ + qrow0 + l15) * HD + quad * 8;
  half8 qf[2][2];
  qf[0][0] = *(const half8*)qptr;
  qf[0][1] = *(const half8*)(qptr + 32);
  qf[1][0] = *(const half8*)(qptr + 16 * HD);
  qf[1][1] = *(const half8*)(qptr + 16 * HD + 32);
#pragma unroll
  for (int q2 = 0; q2 < 2; q2++)
#pragma unroll
    for (int ks = 0; ks < 2; ks++)
#pragma unroll
      for (int j = 0; j < 8; j++) qf[q2][ks][j] *= (f16)0.125f;

  f32x4 zero = {0.f, 0.f, 0.f, 0.f};
  float l_acc[2] = {0.f, 0.f};
  f32x4 o[2][4];
#pragma unroll
  for (int q2 = 0; q2 < 2; q2++)
#pragma unroll
    for (int nt = 0; nt < 4; nt++) o[q2][nt] = zero;

  // swizzled LDS read offsets (halves): row*64 + (chunk ^ (row&7))*8
  int swz0 = (quad ^ (l15 & 7)) * 8;        // log chunks 0..3
  int swz1 = ((quad + 4) ^ (l15 & 7)) * 8;  // log chunks 4..7

  // cooperative staging: K tile (64t x 64d) + V tile (64d x 64t)
  auto stage = [&](int kv0) {
#pragma unroll
    for (int rd = 0; rd < 4; rd++) {
      int row = rd * 16 + srow;
      int pc = schunk ^ (row & 7);
      gload_lds16(kbase + ((size_t)(kv0 + row) << 6) + pc * 8,
                  &Kls[rd * 1024 + w * 512]);
      gload_lds16(vbase + ((size_t)row * SEQ) + kv0 + pc * 8,
                  &Vls[rd * 1024 + w * 512]);
    }
  };

  stage(0);

  for (int kv0 = 0; kv0 < SEQ; kv0 += 64) {
    __syncthreads();  // staged tile visible (barrier drains vmcnt)

    // ---- K fragments from LDS (shared across both q-tiles) ----
    half8 kf0[4], kf1[4];
#pragma unroll
    for (int tt = 0; tt < 4; tt++) {
      int row = tt * 16 + l15;
      kf0[tt] = *(const half8*)&Kls[row * 64 + swz0];
      kf1[tt] = *(const half8*)&Kls[row * 64 + swz1];
    }

    // ---- per q-tile: S^T, softmax, in-register P repack ----
    half8 pa[2][2];  // PV A-fragments, k-slice ks
#pragma unroll
    for (int q2 = 0; q2 < 2; q2++) {
      f32x4 sc[4];
#pragma unroll
      for (int tt = 0; tt < 4; tt++) {
        sc[tt] = __builtin_amdgcn_mfma_f32_16x16x32_f16(kf0[tt], qf[q2][0], zero, 0, 0, 0);
        sc[tt] = __builtin_amdgcn_mfma_f32_16x16x32_f16(kf1[tt], qf[q2][1], sc[tt], 0, 0, 0);
      }
      float ps = 0.f;
#pragma unroll
      for (int tt = 0; tt < 4; tt++)
#pragma unroll
        for (int r = 0; r < 4; r++) { sc[tt][r] = __expf(sc[tt][r]); ps += sc[tt][r]; }
      ps += __shfl_xor(ps, 16);
      ps += __shfl_xor(ps, 32);
      l_acc[q2] += ps;

      // pack P to f16 words: W[tt][0]=(p0,p1), W[tt][1]=(p2,p3)
      unsigned wp[4][2];
#pragma unroll
      for (int tt = 0; tt < 4; tt++) {
        wp[tt][0] = pk16(sc[tt][0], sc[tt][1]);
        wp[tt][1] = pk16(sc[tt][2], sc[tt][3]);
      }
      // route to A-fragment layout: pa[ks][j] = P[l15][ks*32+quad*8+j]
#pragma unroll
      for (int ks = 0; ks < 2; ks++) {
        u32x4 pw;
#pragma unroll
        for (int i = 0; i < 2; i++) {
          unsigned a, bb, x, y;
          swap32(wp[2 * ks][i], wp[2 * ks + 1][i], a, bb);
          swap16(a, bb, x, y);
          pw[i] = x;       // j = 4*i .. 4*i+1  (half 0)
          pw[2 + i] = y;   // j = 4+... (half 1)
        }
        pa[q2][ks] = __builtin_bit_cast(half8, pw);
      }
    }

    // ---- V fragments from LDS (shared across both q-tiles) ----
    half8 vf0[4], vf1[4];
#pragma unroll
    for (int nt = 0; nt < 4; nt++) {
      int row = nt * 16 + l15;
      vf0[nt] = *(const half8*)&Vls[row * 64 + swz0];
      vf1[nt] = *(const half8*)&Vls[row * 64 + swz1];
    }

    __syncthreads();  // all K/V LDS reads of this tile complete

    if (kv0 + 64 < SEQ) stage(kv0 + 64);  // issue next tile; hides under PV

    // ---- O += P V (pure register) ----
#pragma unroll
    for (int q2 = 0; q2 < 2; q2++)
#pragma unroll
      for (int ks = 0; ks < 2; ks++)
#pragma unroll
        for (int nt = 0; nt < 4; nt++)
          o[q2][nt] = __builtin_amdgcn_mfma_f32_16x16x32_f16(pa[q2][ks], ks ? vf1[nt] : vf0[nt], o[q2][nt], 0, 0, 0);
  }

#pragma unroll
  for (int q2 = 0; q2 < 2; q2++) {
    float linv[4];
#pragma unroll
    for (int r = 0; r < 4; r++) linv[r] = 1.0f / __shfl(l_acc[q2], quad * 4 + r);
#pragma unroll
    for (int nt = 0; nt < 4; nt++) {
#pragma unroll
      for (int r = 0; r < 4; r++) {
        int s = qrow0 + q2 * 16 + quad * 4 + r;
        out[((size_t)b * SEQ + s) * RES + h * HD + nt * 16 + l15] = o[q2][nt][r] * linv[r];
      }
    }
  }
}

extern "C" void kernel_launch(void* const* d_in, const int* in_sizes, int n_in,
                              void* d_out, int out_size, void* d_ws, size_t ws_size,
                              hipStream_t stream) {
  (void)in_sizes; (void)n_in; (void)out_size; (void)ws_size;
  const float* x  = (const float*)d_in[0];
  const float* Wq = (const float*)d_in[1];
  const float* Wk = (const float*)d_in[2];
  const float* Wv = (const float*)d_in[3];
  float* out = (float*)d_out;

  // workspace layout (fp16): xh 8MB | Wt 6MB | Qh 8MB | Kh 8MB | Vt 8MB = 38MB
  f16* xh = (f16*)d_ws;
  f16* Wt = xh + (size_t)M_ROWS * RES;
  f16* Qh = Wt + (size_t)3 * RES * RES;
  f16* Kh = Qh + (size_t)BATCH * NH * SEQ * HD;
  f16* Vt = Kh + (size_t)BATCH * NH * SEQ * HD;

  prep_kernel<<<2048 + 3072, 256, 0, stream>>>(x, Wq, Wk, Wv, xh, Wt);
  proj_gemm_kernel<<<dim3(M_ROWS / 128, RES / 128, 3), 256, 0, stream>>>(xh, Wt, Qh, Kh, Vt);
  flash_kernel<<<1024, 128, 0, stream>>>(Qh, Kh, Vt, out);
}